// Round 21
// baseline (55.968 us; speedup 1.0000x reference)
//
#include <hip/hip_runtime.h>
#include <math.h>

#define NSEQ 256
#define SLEN 48
#define DIN  64
#define NCH  8
#define LOG2E 1.4426950408889634f

typedef _Float16 half8  __attribute__((ext_vector_type(8)));
typedef __fp16   fp16x2 __attribute__((ext_vector_type(2)));
typedef _Float16 h2t    __attribute__((ext_vector_type(2)));
typedef float    f32x4  __attribute__((ext_vector_type(4)));

union U8  { _Float16 h[8]; uint4 u; unsigned int w[4]; half8 v; };
union U2  { _Float16 h[4]; uint2 u; };
union UCV { fp16x2 f; h2t h; unsigned int i; };
union UFI { float f; int i; };

// DPP 64-lane sum: 6 VALU adds, no DS pipe. Result valid in lane 63.
__device__ __forceinline__ float wave_sum_dpp(float x) {
    UFI v, t;
    v.f = x;
    t.i = __builtin_amdgcn_update_dpp(0, v.i, 0xB1,  0xF, 0xF, true);  // quad_perm [1,0,3,2]
    v.f += t.f;
    t.i = __builtin_amdgcn_update_dpp(0, v.i, 0x4E,  0xF, 0xF, true);  // quad_perm [2,3,0,1]
    v.f += t.f;
    t.i = __builtin_amdgcn_update_dpp(0, v.i, 0x141, 0xF, 0xF, true);  // row_half_mirror
    v.f += t.f;
    t.i = __builtin_amdgcn_update_dpp(0, v.i, 0x140, 0xF, 0xF, true);  // row_mirror
    v.f += t.f;
    t.i = __builtin_amdgcn_update_dpp(0, v.i, 0x142, 0xA, 0xF, false); // row_bcast:15 -> rows 1,3
    v.f += t.f;
    t.i = __builtin_amdgcn_update_dpp(0, v.i, 0x143, 0xC, 0xF, false); // row_bcast:31 -> rows 2,3
    v.f += t.f;
    return v.f;
}

// ---------------- K1: ALL prep fused into one launch ----------------
// blocks 0..126: W1 frag prep | 127..253: W2 frag prep (k-perm pi, *log2e)
// blocks 254..637: embed (zh) | 638..1149: embedT (zhT)
// blocks 1150..1213: mask -> f32 bias table {0,-16384} + out[:,127]
__global__ __launch_bounds__(256) void prep_k(
    const float* __restrict__ values, const float* __restrict__ times,
    const int* __restrict__ mask,
    const float* __restrict__ omega, const float* __restrict__ alpha,
    const float* __restrict__ W1, const float* __restrict__ W2,
    unsigned short* __restrict__ zh, unsigned short* __restrict__ zhT,
    unsigned short* __restrict__ w1f, unsigned short* __restrict__ w2f,
    float* __restrict__ bias, float* __restrict__ out)
{
    const int bid = blockIdx.x;
    if (bid < 254) {
        // ---- weight fragment prep
        const int isW2 = (bid >= 127);
        const float* W = isW2 ? W2 : W1;
        unsigned short* Wf = isW2 ? w2f : w1f;
        const float scale = isW2 ? LOG2E : 1.0f;
        const int d = isW2 ? bid - 127 : bid;
        __shared__ float wl[DIN * DIN];
        const float* src = W + (size_t)d * DIN * DIN;
        for (int k = threadIdx.x; k < DIN * DIN / 4; k += 256)
            ((float4*)wl)[k] = ((const float4*)src)[k];
        __syncthreads();
        for (int rr = 0; rr < 2; ++rr) {
            int idx = threadIdx.x * 2 + rr;
            int fid = idx >> 6, l = idx & 63;
            int mt = fid >> 1, kt = fid & 1, g = l >> 4, c = l & 15;
            U8 t;
            #pragma unroll
            for (int e = 0; e < 8; ++e) {
                int row = isW2 ? (32 * kt + 16 * (e >> 2) + 4 * g + (e & 3))
                               : (32 * kt + 8 * g + e);
                t.h[e] = (_Float16)(wl[row * DIN + (16 * mt + c)] * scale);
            }
            *(uint4*)(Wf + ((size_t)(d * 8 + fid) * 64 + l) * 8) = t.u;
        }
    } else if (bid < 638) {
        // ---- embed: zh[n*s][64], chunk-swizzled
        int id = (bid - 254) * 256 + threadIdx.x;
        int ch = id & 7, ns = id >> 3;
        if (ns >= NSEQ * SLEN) return;
        int s = ns % SLEN;
        float t = times[ns];
        U8 o;
        #pragma unroll
        for (int e = 0; e < 8; ++e) {
            int i = ch * 8 + e;
            float r;
            if (i == 0)       r = omega[0] * t + alpha[0];
            else if (i == 63) r = values[ns];
            else              r = __sinf(t * omega[i] + alpha[i]);
            o.h[e] = (_Float16)r;
        }
        int csw = ch ^ (s & 7);
        *(uint4*)(zh + (size_t)ns * 64 + csw * 8) = o.u;
    } else if (bid < 1150) {
        // ---- embedT: zhT[n][j][s], row stride 56
        int id = (bid - 638) * 256 + threadIdx.x;
        int unit = id & 511, n = id >> 9;
        int sc = unit >> 6;
        if (sc >= 6) return;
        int j = unit & 63;
        int s0 = sc * 8;
        const float* tp = times + n * SLEN + s0;
        float4 t0 = *(const float4*)tp, t1 = *(const float4*)(tp + 4);
        float tv[8] = {t0.x, t0.y, t0.z, t0.w, t1.x, t1.y, t1.z, t1.w};
        U8 o;
        if (j == 0) {
            float om = omega[0], al = alpha[0];
            #pragma unroll
            for (int e = 0; e < 8; ++e) o.h[e] = (_Float16)(om * tv[e] + al);
        } else if (j == 63) {
            const float* vp = values + n * SLEN + s0;
            float4 v0 = *(const float4*)vp, v1 = *(const float4*)(vp + 4);
            float vv[8] = {v0.x, v0.y, v0.z, v0.w, v1.x, v1.y, v1.z, v1.w};
            #pragma unroll
            for (int e = 0; e < 8; ++e) o.h[e] = (_Float16)vv[e];
        } else {
            float om = omega[j], al = alpha[j];
            #pragma unroll
            for (int e = 0; e < 8; ++e) o.h[e] = (_Float16)__sinf(tv[e] * om + al);
        }
        *(uint4*)(zhT + (size_t)n * 3584 + j * 56 + s0) = o.u;
    } else {
        // ---- mask -> bias table {0,-16384} + out[:,127]
        int wid  = ((bid - 1150) * 256 + threadIdx.x) >> 6;   // n
        int lane = threadIdx.x & 63;
        if (wid >= NSEQ) return;
        int mv = (lane < SLEN) ? mask[wid * SLEN + lane] : 0;
        unsigned long long b = __ballot(mv != 0);
        if (lane < SLEN) bias[wid * SLEN + lane] = mv ? 0.f : -16384.f;
        if (lane == 0) out[wid * 128 + 127] = b ? 1.f : 0.f;
    }
}

// ---------------- K4: main fused kernel ----------------
// = r20 (512-thread blocks, launch_bounds(512,2) no-spill, zero LDS/barriers,
// XCD remap, rotated zf prefetch, b1-as-C, pack-relu, ones-MFMA den, fdot2
// num, b2 deleted, DPP reduce, bias table, bare v_exp) + NEW critical-path
// cuts:
//  (1) den: TWO PARALLEL MFMAs + scalar add (dep depth 2 -> 1, ~-40 cyc)
//  (2) num: two 3-deep fdot2 chains + add (depth 6 -> 3+1, ~-24 cyc)
//  (3) s_setprio(1) around MFMA clusters (T5; independent non-lockstep waves
//      = the attn-like case where it measured +4-7%)
__global__ __launch_bounds__(512, 2) void filter_k(
    const unsigned short* __restrict__ zh,
    const unsigned short* __restrict__ zhT,
    const float* __restrict__ bias,
    const unsigned short* __restrict__ w1f, const unsigned short* __restrict__ w2f,
    const float* __restrict__ b1,
    float* __restrict__ out)
{
    const int tid = threadIdx.x;
    const int w = tid >> 6, lane = tid & 63;
    const int g = lane >> 4, c = lane & 15;

    // XCD-aware remap: 512 blocks; xcd = lin%8, slot = lin/8 (0..63)
    const int lin   = blockIdx.y * 32 + blockIdx.x;
    const int xcd   = lin & 7, slot = lin >> 3;
    const int octet = xcd * 2 + (slot & 1);     // 0..15 (2 octets per XCD)
    const int nchk  = slot >> 1;                // 0..31
    const int d = octet * 8 + w;
    if (d >= 127) return;                       // whole-wave exit; no barriers
    const int nb = nchk * NCH;

    // per-d constants (L2-resident, reused across 8 n's)
    half8 w1fr[8], w2fr[8];
    #pragma unroll
    for (int f = 0; f < 8; ++f) {
        w1fr[f] = *(const half8*)(w1f + ((size_t)(d * 8 + f) * 64 + lane) * 8);
        w2fr[f] = *(const half8*)(w2f + ((size_t)(d * 8 + f) * 64 + lane) * 8);
    }
    f32x4 b1q[4];
    #pragma unroll
    for (int hm = 0; hm < 4; ++hm)
        b1q[hm] = *(const f32x4*)(b1 + d * DIN + 16 * hm + 4 * g);

    // hoisted global-address offsets (element units)
    int zoff[2][3];   // b128 frag reads: row s=16st+c, chunk (4kt+g)^(s&7)
    #pragma unroll
    for (int kt = 0; kt < 2; ++kt)
        #pragma unroll
        for (int st = 0; st < 3; ++st) {
            int s = 16 * st + c;
            zoff[kt][st] = s * 64 + (((4 * kt + g) ^ (s & 7)) << 3);
        }
    const int ztbase = c * 56 + 4 * g;   // zT: row j=16jt+c, s=16st+4g

    const fp16x2 zero2 = {(__fp16)0.f, (__fp16)0.f};
    U8 ones;
    #pragma unroll
    for (int e = 0; e < 8; ++e) ones.h[e] = (_Float16)1.f;
    const f32x4 zero4 = {0.f, 0.f, 0.f, 0.f};

    // ---- preload unit 0's zf (rotation seed)
    half8 zf[2][3];
    {
        const unsigned short* zl = zh + (size_t)nb * 3072;
        #pragma unroll
        for (int kt = 0; kt < 2; ++kt)
            #pragma unroll
            for (int st = 0; st < 3; ++st)
                zf[kt][st] = *(const half8*)(zl + zoff[kt][st]);
    }

    #pragma unroll 1
    for (int ni = 0; ni < NCH; ++ni) {
        const int n = nb + ni;
        const unsigned short* zt = zhT + (size_t)n * 3584;

        // mask bias per (st): s = 16st+4g+r, from precomputed f32 table
        const float* bn = bias + n * SLEN;
        f32x4 binit[3];
        #pragma unroll
        for (int st = 0; st < 3; ++st)
            binit[st] = *(const f32x4*)(bn + 16 * st + 4 * g);

        // ---- layer 1: H^T = W1^T x Z^T (b1 enters as kt=0's C-operand)
        __builtin_amdgcn_s_setprio(1);
        f32x4 aH[4][3];
        #pragma unroll
        for (int hm = 0; hm < 4; ++hm)
            #pragma unroll
            for (int st = 0; st < 3; ++st) {
                aH[hm][st] = __builtin_amdgcn_mfma_f32_16x16x32_f16(
                    w1fr[hm * 2 + 0], zf[0][st], b1q[hm], 0, 0, 0);
                aH[hm][st] = __builtin_amdgcn_mfma_f32_16x16x32_f16(
                    w1fr[hm * 2 + 1], zf[1][st], aH[hm][st], 0, 0, 0);
            }
        __builtin_amdgcn_s_setprio(0);

        // ---- rotation: zf consumed -> issue next unit's zf now
        if (ni + 1 < NCH) {
            const unsigned short* zl = zh + (size_t)(n + 1) * 3072;
            #pragma unroll
            for (int kt = 0; kt < 2; ++kt)
                #pragma unroll
                for (int st = 0; st < 3; ++st)
                    zf[kt][st] = *(const half8*)(zl + zoff[kt][st]);
        }

        // pack-then-relu: cvt_pkrtz -> packed max with 0 (registers only)
        unsigned int pk[4][3][2];
        #pragma unroll
        for (int hm = 0; hm < 4; ++hm)
            #pragma unroll
            for (int st = 0; st < 3; ++st) {
                UCV a, b;
                a.f = __builtin_elementwise_max(
                    __builtin_amdgcn_cvt_pkrtz(aH[hm][st][0], aH[hm][st][1]), zero2);
                b.f = __builtin_elementwise_max(
                    __builtin_amdgcn_cvt_pkrtz(aH[hm][st][2], aH[hm][st][3]), zero2);
                pk[hm][st][0] = a.i;
                pk[hm][st][1] = b.i;
            }

        // ---- per-jt: L2 MFMA (k-permuted, A lane-local; binit as C) +
        //      exp/pack + parallel ones-MFMA den + split fdot2 num
        float part = 0.f;
        #pragma unroll
        for (int jt = 0; jt < 4; ++jt) {
            __builtin_amdgcn_s_setprio(1);
            f32x4 aL3[3];
            #pragma unroll
            for (int st = 0; st < 3; ++st) {
                U8 hfu;
                hfu.w[0] = pk[0][st][0];
                hfu.w[1] = pk[0][st][1];
                hfu.w[2] = pk[1][st][0];
                hfu.w[3] = pk[1][st][1];
                aL3[st] = __builtin_amdgcn_mfma_f32_16x16x32_f16(
                    hfu.v, w2fr[jt * 2 + 0], binit[st], 0, 0, 0);
                hfu.w[0] = pk[2][st][0];
                hfu.w[1] = pk[2][st][1];
                hfu.w[2] = pk[3][st][0];
                hfu.w[3] = pk[3][st][1];
                aL3[st] = __builtin_amdgcn_mfma_f32_16x16x32_f16(
                    hfu.v, w2fr[jt * 2 + 1], aL3[st], 0, 0, 0);
            }
            __builtin_amdgcn_s_setprio(0);
            // exp -> packed f16 e-words (bare v_exp_f32)
            UCV p01[3], p23[3];
            #pragma unroll
            for (int st = 0; st < 3; ++st) {
                float v0 = __builtin_amdgcn_exp2f(aL3[st][0]);
                float v1 = __builtin_amdgcn_exp2f(aL3[st][1]);
                float v2 = __builtin_amdgcn_exp2f(aL3[st][2]);
                float v3 = __builtin_amdgcn_exp2f(aL3[st][3]);
                p01[st].f = __builtin_amdgcn_cvt_pkrtz(v0, v1);
                p23[st].f = __builtin_amdgcn_cvt_pkrtz(v2, v3);
            }
            // den via TWO PARALLEL ones-MFMAs + scalar add (depth 1)
            U8 ef0, ef1;
            ef0.w[0] = p01[0].i; ef0.w[1] = p23[0].i;
            ef0.w[2] = p01[1].i; ef0.w[3] = p23[1].i;
            ef1.w[0] = p01[2].i; ef1.w[1] = p23[2].i;
            ef1.w[2] = 0u;       ef1.w[3] = 0u;
            __builtin_amdgcn_s_setprio(1);
            f32x4 dva = __builtin_amdgcn_mfma_f32_16x16x32_f16(
                ones.v, ef0.v, zero4, 0, 0, 0);
            f32x4 dvb = __builtin_amdgcn_mfma_f32_16x16x32_f16(
                ones.v, ef1.v, zero4, 0, 0, 0);
            __builtin_amdgcn_s_setprio(0);
            float den = dva[0] + dvb[0];
            // num via two parallel 3-deep fdot2 chains
            float numa = 0.f, numb = 0.f;
            {
                U2 zu0, zu1, zu2;
                zu0.u = *(const uint2*)(zt + ztbase + jt * 896 + 0 * 16);
                zu1.u = *(const uint2*)(zt + ztbase + jt * 896 + 1 * 16);
                zu2.u = *(const uint2*)(zt + ztbase + jt * 896 + 2 * 16);
                UCV za, zb;
                za.i = zu0.u.x; zb.i = zu0.u.y;
                numa = __builtin_amdgcn_fdot2(p01[0].h, za.h, numa, false);
                numb = __builtin_amdgcn_fdot2(p23[0].h, zb.h, numb, false);
                za.i = zu1.u.x; zb.i = zu1.u.y;
                numa = __builtin_amdgcn_fdot2(p01[1].h, za.h, numa, false);
                numb = __builtin_amdgcn_fdot2(p23[1].h, zb.h, numb, false);
                za.i = zu2.u.x; zb.i = zu2.u.y;
                numa = __builtin_amdgcn_fdot2(p01[2].h, za.h, numa, false);
                numb = __builtin_amdgcn_fdot2(p23[2].h, zb.h, numb, false);
            }
            part = fmaf(numa + numb, __builtin_amdgcn_rcpf(den), part);
        }
        // ---- DPP 64-lane reduce (VALU only, no DS); total lands in lane 63
        part = wave_sum_dpp(part);
        if (lane == 63) out[n * 128 + d] = part;
    }
}

extern "C" void kernel_launch(void* const* d_in, const int* in_sizes, int n_in,
                              void* d_out, int out_size, void* d_ws, size_t ws_size,
                              hipStream_t stream) {
    const float* values = (const float*)d_in[0];
    const float* times  = (const float*)d_in[1];
    const int*   mask   = (const int*)d_in[2];
    const float* omega  = (const float*)d_in[3];
    const float* alpha  = (const float*)d_in[4];
    const float* W1     = (const float*)d_in[5];
    const float* b1     = (const float*)d_in[6];
    const float* W2     = (const float*)d_in[7];
    // b2 (d_in[8]) cancels in softmax (constant along s). Not read.
    float* out = (float*)d_out;

    unsigned short* zh  = (unsigned short*)d_ws;                 // 786432 f16
    unsigned short* zhT = zh  + (size_t)786432;                  // 917504 f16
    unsigned short* w1f = zhT + (size_t)917504;                  // 520192 f16
    unsigned short* w2f = w1f + (size_t)520192;                  // 520192 f16
    float* bias = (float*)(w2f + (size_t)520192);                // 12288 f32

    prep_k<<<dim3(1214), dim3(256), 0, stream>>>(
        values, times, mask, omega, alpha, W1, W2,
        zh, zhT, w1f, w2f, bias, out);
    filter_k<<<dim3(32, 16), dim3(512), 0, stream>>>(
        zh, zhT, bias, w1f, w2f, b1, out);
}

// Round 22
// 49.854 us; speedup vs baseline: 1.1226x; 1.1226x over previous
//
#include <hip/hip_runtime.h>
#include <math.h>

#define NSEQ 256
#define SLEN 48
#define DIN  64
#define NCH  8
#define LOG2E 1.4426950408889634f

typedef _Float16 half8  __attribute__((ext_vector_type(8)));
typedef __fp16   fp16x2 __attribute__((ext_vector_type(2)));
typedef _Float16 h2t    __attribute__((ext_vector_type(2)));
typedef float    f32x4  __attribute__((ext_vector_type(4)));

union U8  { _Float16 h[8]; uint4 u; unsigned int w[4]; half8 v; };
union U2  { _Float16 h[4]; uint2 u; };
union UCV { fp16x2 f; h2t h; unsigned int i; };
union UFI { float f; int i; };

// DPP 64-lane sum: 6 VALU adds, no DS pipe. Result valid in lane 63.
__device__ __forceinline__ float wave_sum_dpp(float x) {
    UFI v, t;
    v.f = x;
    t.i = __builtin_amdgcn_update_dpp(0, v.i, 0xB1,  0xF, 0xF, true);  // quad_perm [1,0,3,2]
    v.f += t.f;
    t.i = __builtin_amdgcn_update_dpp(0, v.i, 0x4E,  0xF, 0xF, true);  // quad_perm [2,3,0,1]
    v.f += t.f;
    t.i = __builtin_amdgcn_update_dpp(0, v.i, 0x141, 0xF, 0xF, true);  // row_half_mirror
    v.f += t.f;
    t.i = __builtin_amdgcn_update_dpp(0, v.i, 0x140, 0xF, 0xF, true);  // row_mirror
    v.f += t.f;
    t.i = __builtin_amdgcn_update_dpp(0, v.i, 0x142, 0xA, 0xF, false); // row_bcast:15 -> rows 1,3
    v.f += t.f;
    t.i = __builtin_amdgcn_update_dpp(0, v.i, 0x143, 0xC, 0xF, false); // row_bcast:31 -> rows 2,3
    v.f += t.f;
    return v.f;
}

// ---------------- K1: ALL prep fused into one launch ----------------
// blocks 0..126: W1 frag prep | 127..253: W2 frag prep (k-perm pi, *log2e)
// blocks 254..637: embed (zh) | 638..1149: embedT (zhT)
// blocks 1150..1213: mask -> f32 bias table {0,-16384} + out[:,127]
__global__ __launch_bounds__(256) void prep_k(
    const float* __restrict__ values, const float* __restrict__ times,
    const int* __restrict__ mask,
    const float* __restrict__ omega, const float* __restrict__ alpha,
    const float* __restrict__ W1, const float* __restrict__ W2,
    unsigned short* __restrict__ zh, unsigned short* __restrict__ zhT,
    unsigned short* __restrict__ w1f, unsigned short* __restrict__ w2f,
    float* __restrict__ bias, float* __restrict__ out)
{
    const int bid = blockIdx.x;
    if (bid < 254) {
        // ---- weight fragment prep
        const int isW2 = (bid >= 127);
        const float* W = isW2 ? W2 : W1;
        unsigned short* Wf = isW2 ? w2f : w1f;
        const float scale = isW2 ? LOG2E : 1.0f;
        const int d = isW2 ? bid - 127 : bid;
        __shared__ float wl[DIN * DIN];
        const float* src = W + (size_t)d * DIN * DIN;
        for (int k = threadIdx.x; k < DIN * DIN / 4; k += 256)
            ((float4*)wl)[k] = ((const float4*)src)[k];
        __syncthreads();
        for (int rr = 0; rr < 2; ++rr) {
            int idx = threadIdx.x * 2 + rr;
            int fid = idx >> 6, l = idx & 63;
            int mt = fid >> 1, kt = fid & 1, g = l >> 4, c = l & 15;
            U8 t;
            #pragma unroll
            for (int e = 0; e < 8; ++e) {
                int row = isW2 ? (32 * kt + 16 * (e >> 2) + 4 * g + (e & 3))
                               : (32 * kt + 8 * g + e);
                t.h[e] = (_Float16)(wl[row * DIN + (16 * mt + c)] * scale);
            }
            *(uint4*)(Wf + ((size_t)(d * 8 + fid) * 64 + l) * 8) = t.u;
        }
    } else if (bid < 638) {
        // ---- embed: zh[n*s][64], chunk-swizzled
        int id = (bid - 254) * 256 + threadIdx.x;
        int ch = id & 7, ns = id >> 3;
        if (ns >= NSEQ * SLEN) return;
        int s = ns % SLEN;
        float t = times[ns];
        U8 o;
        #pragma unroll
        for (int e = 0; e < 8; ++e) {
            int i = ch * 8 + e;
            float r;
            if (i == 0)       r = omega[0] * t + alpha[0];
            else if (i == 63) r = values[ns];
            else              r = __sinf(t * omega[i] + alpha[i]);
            o.h[e] = (_Float16)r;
        }
        int csw = ch ^ (s & 7);
        *(uint4*)(zh + (size_t)ns * 64 + csw * 8) = o.u;
    } else if (bid < 1150) {
        // ---- embedT: zhT[n][j][s], row stride 56
        int id = (bid - 638) * 256 + threadIdx.x;
        int unit = id & 511, n = id >> 9;
        int sc = unit >> 6;
        if (sc >= 6) return;
        int j = unit & 63;
        int s0 = sc * 8;
        const float* tp = times + n * SLEN + s0;
        float4 t0 = *(const float4*)tp, t1 = *(const float4*)(tp + 4);
        float tv[8] = {t0.x, t0.y, t0.z, t0.w, t1.x, t1.y, t1.z, t1.w};
        U8 o;
        if (j == 0) {
            float om = omega[0], al = alpha[0];
            #pragma unroll
            for (int e = 0; e < 8; ++e) o.h[e] = (_Float16)(om * tv[e] + al);
        } else if (j == 63) {
            const float* vp = values + n * SLEN + s0;
            float4 v0 = *(const float4*)vp, v1 = *(const float4*)(vp + 4);
            float vv[8] = {v0.x, v0.y, v0.z, v0.w, v1.x, v1.y, v1.z, v1.w};
            #pragma unroll
            for (int e = 0; e < 8; ++e) o.h[e] = (_Float16)vv[e];
        } else {
            float om = omega[j], al = alpha[j];
            #pragma unroll
            for (int e = 0; e < 8; ++e) o.h[e] = (_Float16)__sinf(tv[e] * om + al);
        }
        *(uint4*)(zhT + (size_t)n * 3584 + j * 56 + s0) = o.u;
    } else {
        // ---- mask -> bias table {0,-16384} + out[:,127]
        int wid  = ((bid - 1150) * 256 + threadIdx.x) >> 6;   // n
        int lane = threadIdx.x & 63;
        if (wid >= NSEQ) return;
        int mv = (lane < SLEN) ? mask[wid * SLEN + lane] : 0;
        unsigned long long b = __ballot(mv != 0);
        if (lane < SLEN) bias[wid * SLEN + lane] = mv ? 0.f : -16384.f;
        if (lane == 0) out[wid * 128 + 127] = b ? 1.f : 0.f;
    }
}

// ---------------- K4: main fused kernel ----------------
// = r20 (512-thread blocks, launch_bounds(512,2) no-spill, zero LDS/barriers,
// XCD remap, rotated zf prefetch, b1-as-C, pack-relu, ones-MFMA den, fdot2
// num, b2 deleted, DPP reduce, bias table, bare v_exp)
// + r21's depth cuts (parallel den MFMAs depth 2->1; num split into two
//   3-deep fdot2 chains)
// - r21's s_setprio REMOVED (A/B isolation: symmetric waves -> setprio hurts,
//   matching m190's GEMM measurement; r21 regressed 46.7->50 us)
__global__ __launch_bounds__(512, 2) void filter_k(
    const unsigned short* __restrict__ zh,
    const unsigned short* __restrict__ zhT,
    const float* __restrict__ bias,
    const unsigned short* __restrict__ w1f, const unsigned short* __restrict__ w2f,
    const float* __restrict__ b1,
    float* __restrict__ out)
{
    const int tid = threadIdx.x;
    const int w = tid >> 6, lane = tid & 63;
    const int g = lane >> 4, c = lane & 15;

    // XCD-aware remap: 512 blocks; xcd = lin%8, slot = lin/8 (0..63)
    const int lin   = blockIdx.y * 32 + blockIdx.x;
    const int xcd   = lin & 7, slot = lin >> 3;
    const int octet = xcd * 2 + (slot & 1);     // 0..15 (2 octets per XCD)
    const int nchk  = slot >> 1;                // 0..31
    const int d = octet * 8 + w;
    if (d >= 127) return;                       // whole-wave exit; no barriers
    const int nb = nchk * NCH;

    // per-d constants (L2-resident, reused across 8 n's)
    half8 w1fr[8], w2fr[8];
    #pragma unroll
    for (int f = 0; f < 8; ++f) {
        w1fr[f] = *(const half8*)(w1f + ((size_t)(d * 8 + f) * 64 + lane) * 8);
        w2fr[f] = *(const half8*)(w2f + ((size_t)(d * 8 + f) * 64 + lane) * 8);
    }
    f32x4 b1q[4];
    #pragma unroll
    for (int hm = 0; hm < 4; ++hm)
        b1q[hm] = *(const f32x4*)(b1 + d * DIN + 16 * hm + 4 * g);

    // hoisted global-address offsets (element units)
    int zoff[2][3];   // b128 frag reads: row s=16st+c, chunk (4kt+g)^(s&7)
    #pragma unroll
    for (int kt = 0; kt < 2; ++kt)
        #pragma unroll
        for (int st = 0; st < 3; ++st) {
            int s = 16 * st + c;
            zoff[kt][st] = s * 64 + (((4 * kt + g) ^ (s & 7)) << 3);
        }
    const int ztbase = c * 56 + 4 * g;   // zT: row j=16jt+c, s=16st+4g

    const fp16x2 zero2 = {(__fp16)0.f, (__fp16)0.f};
    U8 ones;
    #pragma unroll
    for (int e = 0; e < 8; ++e) ones.h[e] = (_Float16)1.f;
    const f32x4 zero4 = {0.f, 0.f, 0.f, 0.f};

    // ---- preload unit 0's zf (rotation seed)
    half8 zf[2][3];
    {
        const unsigned short* zl = zh + (size_t)nb * 3072;
        #pragma unroll
        for (int kt = 0; kt < 2; ++kt)
            #pragma unroll
            for (int st = 0; st < 3; ++st)
                zf[kt][st] = *(const half8*)(zl + zoff[kt][st]);
    }

    #pragma unroll 1
    for (int ni = 0; ni < NCH; ++ni) {
        const int n = nb + ni;
        const unsigned short* zt = zhT + (size_t)n * 3584;

        // mask bias per (st): s = 16st+4g+r, from precomputed f32 table
        const float* bn = bias + n * SLEN;
        f32x4 binit[3];
        #pragma unroll
        for (int st = 0; st < 3; ++st)
            binit[st] = *(const f32x4*)(bn + 16 * st + 4 * g);

        // ---- layer 1: H^T = W1^T x Z^T (b1 enters as kt=0's C-operand)
        f32x4 aH[4][3];
        #pragma unroll
        for (int hm = 0; hm < 4; ++hm)
            #pragma unroll
            for (int st = 0; st < 3; ++st) {
                aH[hm][st] = __builtin_amdgcn_mfma_f32_16x16x32_f16(
                    w1fr[hm * 2 + 0], zf[0][st], b1q[hm], 0, 0, 0);
                aH[hm][st] = __builtin_amdgcn_mfma_f32_16x16x32_f16(
                    w1fr[hm * 2 + 1], zf[1][st], aH[hm][st], 0, 0, 0);
            }

        // ---- rotation: zf consumed -> issue next unit's zf now
        if (ni + 1 < NCH) {
            const unsigned short* zl = zh + (size_t)(n + 1) * 3072;
            #pragma unroll
            for (int kt = 0; kt < 2; ++kt)
                #pragma unroll
                for (int st = 0; st < 3; ++st)
                    zf[kt][st] = *(const half8*)(zl + zoff[kt][st]);
        }

        // pack-then-relu: cvt_pkrtz -> packed max with 0 (registers only)
        unsigned int pk[4][3][2];
        #pragma unroll
        for (int hm = 0; hm < 4; ++hm)
            #pragma unroll
            for (int st = 0; st < 3; ++st) {
                UCV a, b;
                a.f = __builtin_elementwise_max(
                    __builtin_amdgcn_cvt_pkrtz(aH[hm][st][0], aH[hm][st][1]), zero2);
                b.f = __builtin_elementwise_max(
                    __builtin_amdgcn_cvt_pkrtz(aH[hm][st][2], aH[hm][st][3]), zero2);
                pk[hm][st][0] = a.i;
                pk[hm][st][1] = b.i;
            }

        // ---- per-jt: L2 MFMA (k-permuted, A lane-local; binit as C) +
        //      exp/pack + parallel ones-MFMA den + split fdot2 num
        float part = 0.f;
        #pragma unroll
        for (int jt = 0; jt < 4; ++jt) {
            f32x4 aL3[3];
            #pragma unroll
            for (int st = 0; st < 3; ++st) {
                U8 hfu;
                hfu.w[0] = pk[0][st][0];
                hfu.w[1] = pk[0][st][1];
                hfu.w[2] = pk[1][st][0];
                hfu.w[3] = pk[1][st][1];
                aL3[st] = __builtin_amdgcn_mfma_f32_16x16x32_f16(
                    hfu.v, w2fr[jt * 2 + 0], binit[st], 0, 0, 0);
                hfu.w[0] = pk[2][st][0];
                hfu.w[1] = pk[2][st][1];
                hfu.w[2] = pk[3][st][0];
                hfu.w[3] = pk[3][st][1];
                aL3[st] = __builtin_amdgcn_mfma_f32_16x16x32_f16(
                    hfu.v, w2fr[jt * 2 + 1], aL3[st], 0, 0, 0);
            }
            // exp -> packed f16 e-words (bare v_exp_f32)
            UCV p01[3], p23[3];
            #pragma unroll
            for (int st = 0; st < 3; ++st) {
                float v0 = __builtin_amdgcn_exp2f(aL3[st][0]);
                float v1 = __builtin_amdgcn_exp2f(aL3[st][1]);
                float v2 = __builtin_amdgcn_exp2f(aL3[st][2]);
                float v3 = __builtin_amdgcn_exp2f(aL3[st][3]);
                p01[st].f = __builtin_amdgcn_cvt_pkrtz(v0, v1);
                p23[st].f = __builtin_amdgcn_cvt_pkrtz(v2, v3);
            }
            // den via TWO PARALLEL ones-MFMAs + scalar add (depth 1)
            U8 ef0, ef1;
            ef0.w[0] = p01[0].i; ef0.w[1] = p23[0].i;
            ef0.w[2] = p01[1].i; ef0.w[3] = p23[1].i;
            ef1.w[0] = p01[2].i; ef1.w[1] = p23[2].i;
            ef1.w[2] = 0u;       ef1.w[3] = 0u;
            f32x4 dva = __builtin_amdgcn_mfma_f32_16x16x32_f16(
                ones.v, ef0.v, zero4, 0, 0, 0);
            f32x4 dvb = __builtin_amdgcn_mfma_f32_16x16x32_f16(
                ones.v, ef1.v, zero4, 0, 0, 0);
            float den = dva[0] + dvb[0];
            // num via two parallel 3-deep fdot2 chains
            float numa = 0.f, numb = 0.f;
            {
                U2 zu0, zu1, zu2;
                zu0.u = *(const uint2*)(zt + ztbase + jt * 896 + 0 * 16);
                zu1.u = *(const uint2*)(zt + ztbase + jt * 896 + 1 * 16);
                zu2.u = *(const uint2*)(zt + ztbase + jt * 896 + 2 * 16);
                UCV za, zb;
                za.i = zu0.u.x; zb.i = zu0.u.y;
                numa = __builtin_amdgcn_fdot2(p01[0].h, za.h, numa, false);
                numb = __builtin_amdgcn_fdot2(p23[0].h, zb.h, numb, false);
                za.i = zu1.u.x; zb.i = zu1.u.y;
                numa = __builtin_amdgcn_fdot2(p01[1].h, za.h, numa, false);
                numb = __builtin_amdgcn_fdot2(p23[1].h, zb.h, numb, false);
                za.i = zu2.u.x; zb.i = zu2.u.y;
                numa = __builtin_amdgcn_fdot2(p01[2].h, za.h, numa, false);
                numb = __builtin_amdgcn_fdot2(p23[2].h, zb.h, numb, false);
            }
            part = fmaf(numa + numb, __builtin_amdgcn_rcpf(den), part);
        }
        // ---- DPP 64-lane reduce (VALU only, no DS); total lands in lane 63
        part = wave_sum_dpp(part);
        if (lane == 63) out[n * 128 + d] = part;
    }
}

extern "C" void kernel_launch(void* const* d_in, const int* in_sizes, int n_in,
                              void* d_out, int out_size, void* d_ws, size_t ws_size,
                              hipStream_t stream) {
    const float* values = (const float*)d_in[0];
    const float* times  = (const float*)d_in[1];
    const int*   mask   = (const int*)d_in[2];
    const float* omega  = (const float*)d_in[3];
    const float* alpha  = (const float*)d_in[4];
    const float* W1     = (const float*)d_in[5];
    const float* b1     = (const float*)d_in[6];
    const float* W2     = (const float*)d_in[7];
    // b2 (d_in[8]) cancels in softmax (constant along s). Not read.
    float* out = (float*)d_out;

    unsigned short* zh  = (unsigned short*)d_ws;                 // 786432 f16
    unsigned short* zhT = zh  + (size_t)786432;                  // 917504 f16
    unsigned short* w1f = zhT + (size_t)917504;                  // 520192 f16
    unsigned short* w2f = w1f + (size_t)520192;                  // 520192 f16
    float* bias = (float*)(w2f + (size_t)520192);                // 12288 f32

    prep_k<<<dim3(1214), dim3(256), 0, stream>>>(
        values, times, mask, omega, alpha, W1, W2,
        zh, zhT, w1f, w2f, bias, out);
    filter_k<<<dim3(32, 16), dim3(512), 0, stream>>>(
        zh, zhT, bias, w1f, w2f, b1, out);
}

// Round 23
// 49.558 us; speedup vs baseline: 1.1293x; 1.0060x over previous
//
#include <hip/hip_runtime.h>
#include <math.h>

#define NSEQ 256
#define SLEN 48
#define DIN  64
#define NCH  8
#define LOG2E 1.4426950408889634f

typedef _Float16 half8  __attribute__((ext_vector_type(8)));
typedef __fp16   fp16x2 __attribute__((ext_vector_type(2)));
typedef _Float16 h2t    __attribute__((ext_vector_type(2)));
typedef float    f32x4  __attribute__((ext_vector_type(4)));

union U8  { _Float16 h[8]; uint4 u; unsigned int w[4]; half8 v; };
union U2  { _Float16 h[4]; uint2 u; };
union UCV { fp16x2 f; h2t h; unsigned int i; };
union UFI { float f; int i; };

// DPP 64-lane sum: 6 VALU adds, no DS pipe. Result valid in lane 63.
__device__ __forceinline__ float wave_sum_dpp(float x) {
    UFI v, t;
    v.f = x;
    t.i = __builtin_amdgcn_update_dpp(0, v.i, 0xB1,  0xF, 0xF, true);  // quad_perm [1,0,3,2]
    v.f += t.f;
    t.i = __builtin_amdgcn_update_dpp(0, v.i, 0x4E,  0xF, 0xF, true);  // quad_perm [2,3,0,1]
    v.f += t.f;
    t.i = __builtin_amdgcn_update_dpp(0, v.i, 0x141, 0xF, 0xF, true);  // row_half_mirror
    v.f += t.f;
    t.i = __builtin_amdgcn_update_dpp(0, v.i, 0x140, 0xF, 0xF, true);  // row_mirror
    v.f += t.f;
    t.i = __builtin_amdgcn_update_dpp(0, v.i, 0x142, 0xA, 0xF, false); // row_bcast:15 -> rows 1,3
    v.f += t.f;
    t.i = __builtin_amdgcn_update_dpp(0, v.i, 0x143, 0xC, 0xF, false); // row_bcast:31 -> rows 2,3
    v.f += t.f;
    return v.f;
}

// ---------------- K1: ALL prep fused into one launch ----------------
// blocks 0..126: W1 frag prep | 127..253: W2 frag prep (k-perm pi, *log2e)
// blocks 254..637: embed (zh) | 638..1149: embedT (zhT)
// blocks 1150..1213: mask -> f32 bias table {0,-16384} + out[:,127]
__global__ __launch_bounds__(256) void prep_k(
    const float* __restrict__ values, const float* __restrict__ times,
    const int* __restrict__ mask,
    const float* __restrict__ omega, const float* __restrict__ alpha,
    const float* __restrict__ W1, const float* __restrict__ W2,
    unsigned short* __restrict__ zh, unsigned short* __restrict__ zhT,
    unsigned short* __restrict__ w1f, unsigned short* __restrict__ w2f,
    float* __restrict__ bias, float* __restrict__ out)
{
    const int bid = blockIdx.x;
    if (bid < 254) {
        // ---- weight fragment prep
        const int isW2 = (bid >= 127);
        const float* W = isW2 ? W2 : W1;
        unsigned short* Wf = isW2 ? w2f : w1f;
        const float scale = isW2 ? LOG2E : 1.0f;
        const int d = isW2 ? bid - 127 : bid;
        __shared__ float wl[DIN * DIN];
        const float* src = W + (size_t)d * DIN * DIN;
        for (int k = threadIdx.x; k < DIN * DIN / 4; k += 256)
            ((float4*)wl)[k] = ((const float4*)src)[k];
        __syncthreads();
        for (int rr = 0; rr < 2; ++rr) {
            int idx = threadIdx.x * 2 + rr;
            int fid = idx >> 6, l = idx & 63;
            int mt = fid >> 1, kt = fid & 1, g = l >> 4, c = l & 15;
            U8 t;
            #pragma unroll
            for (int e = 0; e < 8; ++e) {
                int row = isW2 ? (32 * kt + 16 * (e >> 2) + 4 * g + (e & 3))
                               : (32 * kt + 8 * g + e);
                t.h[e] = (_Float16)(wl[row * DIN + (16 * mt + c)] * scale);
            }
            *(uint4*)(Wf + ((size_t)(d * 8 + fid) * 64 + l) * 8) = t.u;
        }
    } else if (bid < 638) {
        // ---- embed: zh[n*s][64], chunk-swizzled
        int id = (bid - 254) * 256 + threadIdx.x;
        int ch = id & 7, ns = id >> 3;
        if (ns >= NSEQ * SLEN) return;
        int s = ns % SLEN;
        float t = times[ns];
        U8 o;
        #pragma unroll
        for (int e = 0; e < 8; ++e) {
            int i = ch * 8 + e;
            float r;
            if (i == 0)       r = omega[0] * t + alpha[0];
            else if (i == 63) r = values[ns];
            else              r = __sinf(t * omega[i] + alpha[i]);
            o.h[e] = (_Float16)r;
        }
        int csw = ch ^ (s & 7);
        *(uint4*)(zh + (size_t)ns * 64 + csw * 8) = o.u;
    } else if (bid < 1150) {
        // ---- embedT: zhT[n][j][s], row stride 56
        int id = (bid - 638) * 256 + threadIdx.x;
        int unit = id & 511, n = id >> 9;
        int sc = unit >> 6;
        if (sc >= 6) return;
        int j = unit & 63;
        int s0 = sc * 8;
        const float* tp = times + n * SLEN + s0;
        float4 t0 = *(const float4*)tp, t1 = *(const float4*)(tp + 4);
        float tv[8] = {t0.x, t0.y, t0.z, t0.w, t1.x, t1.y, t1.z, t1.w};
        U8 o;
        if (j == 0) {
            float om = omega[0], al = alpha[0];
            #pragma unroll
            for (int e = 0; e < 8; ++e) o.h[e] = (_Float16)(om * tv[e] + al);
        } else if (j == 63) {
            const float* vp = values + n * SLEN + s0;
            float4 v0 = *(const float4*)vp, v1 = *(const float4*)(vp + 4);
            float vv[8] = {v0.x, v0.y, v0.z, v0.w, v1.x, v1.y, v1.z, v1.w};
            #pragma unroll
            for (int e = 0; e < 8; ++e) o.h[e] = (_Float16)vv[e];
        } else {
            float om = omega[j], al = alpha[j];
            #pragma unroll
            for (int e = 0; e < 8; ++e) o.h[e] = (_Float16)__sinf(tv[e] * om + al);
        }
        *(uint4*)(zhT + (size_t)n * 3584 + j * 56 + s0) = o.u;
    } else {
        // ---- mask -> bias table {0,-16384} + out[:,127]
        int wid  = ((bid - 1150) * 256 + threadIdx.x) >> 6;   // n
        int lane = threadIdx.x & 63;
        if (wid >= NSEQ) return;
        int mv = (lane < SLEN) ? mask[wid * SLEN + lane] : 0;
        unsigned long long b = __ballot(mv != 0);
        if (lane < SLEN) bias[wid * SLEN + lane] = mv ? 0.f : -16384.f;
        if (lane == 0) out[wid * 128 + 127] = b ? 1.f : 0.f;
    }
}

// ---------------- K4: main fused kernel ----------------
// = r22 (512-thread blocks, launch_bounds(512,2) no-spill, zero LDS/barriers,
// XCD remap, rotated zf prefetch, b1-as-C, pack-relu, parallel ones-MFMA den,
// split fdot2 num, b2 deleted, DPP reduce, bias table, bare v_exp, NO setprio)
// + NEW (single change): ALL 12 zt loads hoisted to the top of the unit body
//   (ztv[4][3] regs, static indices). prep->filter reads cross XCDs (L2s not
//   coherent) so these are ~600-900cyc L3/HBM-path loads; previously issued
//   per-jt right before their fdot2 use = 4 serial stalls/unit. Hoisting puts
//   L1+pack+L2+exp (~2k cyc) between issue and use. +24 VGPR (~120 <= 128).
__global__ __launch_bounds__(512, 2) void filter_k(
    const unsigned short* __restrict__ zh,
    const unsigned short* __restrict__ zhT,
    const float* __restrict__ bias,
    const unsigned short* __restrict__ w1f, const unsigned short* __restrict__ w2f,
    const float* __restrict__ b1,
    float* __restrict__ out)
{
    const int tid = threadIdx.x;
    const int w = tid >> 6, lane = tid & 63;
    const int g = lane >> 4, c = lane & 15;

    // XCD-aware remap: 512 blocks; xcd = lin%8, slot = lin/8 (0..63)
    const int lin   = blockIdx.y * 32 + blockIdx.x;
    const int xcd   = lin & 7, slot = lin >> 3;
    const int octet = xcd * 2 + (slot & 1);     // 0..15 (2 octets per XCD)
    const int nchk  = slot >> 1;                // 0..31
    const int d = octet * 8 + w;
    if (d >= 127) return;                       // whole-wave exit; no barriers
    const int nb = nchk * NCH;

    // per-d constants (reused across 8 n's)
    half8 w1fr[8], w2fr[8];
    #pragma unroll
    for (int f = 0; f < 8; ++f) {
        w1fr[f] = *(const half8*)(w1f + ((size_t)(d * 8 + f) * 64 + lane) * 8);
        w2fr[f] = *(const half8*)(w2f + ((size_t)(d * 8 + f) * 64 + lane) * 8);
    }
    f32x4 b1q[4];
    #pragma unroll
    for (int hm = 0; hm < 4; ++hm)
        b1q[hm] = *(const f32x4*)(b1 + d * DIN + 16 * hm + 4 * g);

    // hoisted global-address offsets (element units)
    int zoff[2][3];   // b128 frag reads: row s=16st+c, chunk (4kt+g)^(s&7)
    #pragma unroll
    for (int kt = 0; kt < 2; ++kt)
        #pragma unroll
        for (int st = 0; st < 3; ++st) {
            int s = 16 * st + c;
            zoff[kt][st] = s * 64 + (((4 * kt + g) ^ (s & 7)) << 3);
        }
    const int ztbase = c * 56 + 4 * g;   // zT: row j=16jt+c, s=16st+4g

    const fp16x2 zero2 = {(__fp16)0.f, (__fp16)0.f};
    U8 ones;
    #pragma unroll
    for (int e = 0; e < 8; ++e) ones.h[e] = (_Float16)1.f;
    const f32x4 zero4 = {0.f, 0.f, 0.f, 0.f};

    // ---- preload unit 0's zf (rotation seed)
    half8 zf[2][3];
    {
        const unsigned short* zl = zh + (size_t)nb * 3072;
        #pragma unroll
        for (int kt = 0; kt < 2; ++kt)
            #pragma unroll
            for (int st = 0; st < 3; ++st)
                zf[kt][st] = *(const half8*)(zl + zoff[kt][st]);
    }

    #pragma unroll 1
    for (int ni = 0; ni < NCH; ++ni) {
        const int n = nb + ni;
        const unsigned short* zt = zhT + (size_t)n * 3584;

        // mask bias per (st): s = 16st+4g+r, from precomputed f32 table
        const float* bn = bias + n * SLEN;
        f32x4 binit[3];
        #pragma unroll
        for (int st = 0; st < 3; ++st)
            binit[st] = *(const f32x4*)(bn + 16 * st + 4 * g);

        // ---- HOISTED zt loads: issue ALL 12 now; consumed after L1+pack+L2
        U2 ztv[4][3];
        #pragma unroll
        for (int jt = 0; jt < 4; ++jt)
            #pragma unroll
            for (int st = 0; st < 3; ++st)
                ztv[jt][st].u = *(const uint2*)(zt + ztbase + jt * 896 + st * 16);

        // ---- layer 1: H^T = W1^T x Z^T (b1 enters as kt=0's C-operand)
        f32x4 aH[4][3];
        #pragma unroll
        for (int hm = 0; hm < 4; ++hm)
            #pragma unroll
            for (int st = 0; st < 3; ++st) {
                aH[hm][st] = __builtin_amdgcn_mfma_f32_16x16x32_f16(
                    w1fr[hm * 2 + 0], zf[0][st], b1q[hm], 0, 0, 0);
                aH[hm][st] = __builtin_amdgcn_mfma_f32_16x16x32_f16(
                    w1fr[hm * 2 + 1], zf[1][st], aH[hm][st], 0, 0, 0);
            }

        // ---- rotation: zf consumed -> issue next unit's zf now
        if (ni + 1 < NCH) {
            const unsigned short* zl = zh + (size_t)(n + 1) * 3072;
            #pragma unroll
            for (int kt = 0; kt < 2; ++kt)
                #pragma unroll
                for (int st = 0; st < 3; ++st)
                    zf[kt][st] = *(const half8*)(zl + zoff[kt][st]);
        }

        // pack-then-relu: cvt_pkrtz -> packed max with 0 (registers only)
        unsigned int pk[4][3][2];
        #pragma unroll
        for (int hm = 0; hm < 4; ++hm)
            #pragma unroll
            for (int st = 0; st < 3; ++st) {
                UCV a, b;
                a.f = __builtin_elementwise_max(
                    __builtin_amdgcn_cvt_pkrtz(aH[hm][st][0], aH[hm][st][1]), zero2);
                b.f = __builtin_elementwise_max(
                    __builtin_amdgcn_cvt_pkrtz(aH[hm][st][2], aH[hm][st][3]), zero2);
                pk[hm][st][0] = a.i;
                pk[hm][st][1] = b.i;
            }

        // ---- per-jt: L2 MFMA (k-permuted, A lane-local; binit as C) +
        //      exp/pack + parallel ones-MFMA den + split fdot2 num
        float part = 0.f;
        #pragma unroll
        for (int jt = 0; jt < 4; ++jt) {
            f32x4 aL3[3];
            #pragma unroll
            for (int st = 0; st < 3; ++st) {
                U8 hfu;
                hfu.w[0] = pk[0][st][0];
                hfu.w[1] = pk[0][st][1];
                hfu.w[2] = pk[1][st][0];
                hfu.w[3] = pk[1][st][1];
                aL3[st] = __builtin_amdgcn_mfma_f32_16x16x32_f16(
                    hfu.v, w2fr[jt * 2 + 0], binit[st], 0, 0, 0);
                hfu.w[0] = pk[2][st][0];
                hfu.w[1] = pk[2][st][1];
                hfu.w[2] = pk[3][st][0];
                hfu.w[3] = pk[3][st][1];
                aL3[st] = __builtin_amdgcn_mfma_f32_16x16x32_f16(
                    hfu.v, w2fr[jt * 2 + 1], aL3[st], 0, 0, 0);
            }
            // exp -> packed f16 e-words (bare v_exp_f32)
            UCV p01[3], p23[3];
            #pragma unroll
            for (int st = 0; st < 3; ++st) {
                float v0 = __builtin_amdgcn_exp2f(aL3[st][0]);
                float v1 = __builtin_amdgcn_exp2f(aL3[st][1]);
                float v2 = __builtin_amdgcn_exp2f(aL3[st][2]);
                float v3 = __builtin_amdgcn_exp2f(aL3[st][3]);
                p01[st].f = __builtin_amdgcn_cvt_pkrtz(v0, v1);
                p23[st].f = __builtin_amdgcn_cvt_pkrtz(v2, v3);
            }
            // den via TWO PARALLEL ones-MFMAs + scalar add (depth 1)
            U8 ef0, ef1;
            ef0.w[0] = p01[0].i; ef0.w[1] = p23[0].i;
            ef0.w[2] = p01[1].i; ef0.w[3] = p23[1].i;
            ef1.w[0] = p01[2].i; ef1.w[1] = p23[2].i;
            ef1.w[2] = 0u;       ef1.w[3] = 0u;
            f32x4 dva = __builtin_amdgcn_mfma_f32_16x16x32_f16(
                ones.v, ef0.v, zero4, 0, 0, 0);
            f32x4 dvb = __builtin_amdgcn_mfma_f32_16x16x32_f16(
                ones.v, ef1.v, zero4, 0, 0, 0);
            float den = dva[0] + dvb[0];
            // num via two parallel 3-deep fdot2 chains (zt already in regs)
            float numa = 0.f, numb = 0.f;
            {
                UCV za, zb;
                za.i = ztv[jt][0].u.x; zb.i = ztv[jt][0].u.y;
                numa = __builtin_amdgcn_fdot2(p01[0].h, za.h, numa, false);
                numb = __builtin_amdgcn_fdot2(p23[0].h, zb.h, numb, false);
                za.i = ztv[jt][1].u.x; zb.i = ztv[jt][1].u.y;
                numa = __builtin_amdgcn_fdot2(p01[1].h, za.h, numa, false);
                numb = __builtin_amdgcn_fdot2(p23[1].h, zb.h, numb, false);
                za.i = ztv[jt][2].u.x; zb.i = ztv[jt][2].u.y;
                numa = __builtin_amdgcn_fdot2(p01[2].h, za.h, numa, false);
                numb = __builtin_amdgcn_fdot2(p23[2].h, zb.h, numb, false);
            }
            part = fmaf(numa + numb, __builtin_amdgcn_rcpf(den), part);
        }
        // ---- DPP 64-lane reduce (VALU only, no DS); total lands in lane 63
        part = wave_sum_dpp(part);
        if (lane == 63) out[n * 128 + d] = part;
    }
}

extern "C" void kernel_launch(void* const* d_in, const int* in_sizes, int n_in,
                              void* d_out, int out_size, void* d_ws, size_t ws_size,
                              hipStream_t stream) {
    const float* values = (const float*)d_in[0];
    const float* times  = (const float*)d_in[1];
    const int*   mask   = (const int*)d_in[2];
    const float* omega  = (const float*)d_in[3];
    const float* alpha  = (const float*)d_in[4];
    const float* W1     = (const float*)d_in[5];
    const float* b1     = (const float*)d_in[6];
    const float* W2     = (const float*)d_in[7];
    // b2 (d_in[8]) cancels in softmax (constant along s). Not read.
    float* out = (float*)d_out;

    unsigned short* zh  = (unsigned short*)d_ws;                 // 786432 f16
    unsigned short* zhT = zh  + (size_t)786432;                  // 917504 f16
    unsigned short* w1f = zhT + (size_t)917504;                  // 520192 f16
    unsigned short* w2f = w1f + (size_t)520192;                  // 520192 f16
    float* bias = (float*)(w2f + (size_t)520192);                // 12288 f32

    prep_k<<<dim3(1214), dim3(256), 0, stream>>>(
        values, times, mask, omega, alpha, W1, W2,
        zh, zhT, w1f, w2f, bias, out);
    filter_k<<<dim3(32, 16), dim3(512), 0, stream>>>(
        zh, zhT, bias, w1f, w2f, b1, out);
}

// Round 24
// 48.117 us; speedup vs baseline: 1.1632x; 1.0299x over previous
//
#include <hip/hip_runtime.h>
#include <math.h>

#define NSEQ 256
#define SLEN 48
#define DIN  64
#define NCH  8
#define LOG2E 1.4426950408889634f

typedef _Float16 half8  __attribute__((ext_vector_type(8)));
typedef __fp16   fp16x2 __attribute__((ext_vector_type(2)));
typedef _Float16 h2t    __attribute__((ext_vector_type(2)));
typedef float    f32x4  __attribute__((ext_vector_type(4)));

union U8  { _Float16 h[8]; uint4 u; unsigned int w[4]; half8 v; };
union U2  { _Float16 h[4]; uint2 u; };
union UCV { fp16x2 f; h2t h; unsigned int i; };
union UFI { float f; int i; };

// DPP 64-lane sum: 6 VALU adds, no DS pipe. Result valid in lane 63.
__device__ __forceinline__ float wave_sum_dpp(float x) {
    UFI v, t;
    v.f = x;
    t.i = __builtin_amdgcn_update_dpp(0, v.i, 0xB1,  0xF, 0xF, true);  // quad_perm [1,0,3,2]
    v.f += t.f;
    t.i = __builtin_amdgcn_update_dpp(0, v.i, 0x4E,  0xF, 0xF, true);  // quad_perm [2,3,0,1]
    v.f += t.f;
    t.i = __builtin_amdgcn_update_dpp(0, v.i, 0x141, 0xF, 0xF, true);  // row_half_mirror
    v.f += t.f;
    t.i = __builtin_amdgcn_update_dpp(0, v.i, 0x140, 0xF, 0xF, true);  // row_mirror
    v.f += t.f;
    t.i = __builtin_amdgcn_update_dpp(0, v.i, 0x142, 0xA, 0xF, false); // row_bcast:15 -> rows 1,3
    v.f += t.f;
    t.i = __builtin_amdgcn_update_dpp(0, v.i, 0x143, 0xC, 0xF, false); // row_bcast:31 -> rows 2,3
    v.f += t.f;
    return v.f;
}

// ---------------- K1: ALL prep fused into one launch ----------------
// blocks 0..126: W1 frag prep | 127..253: W2 frag prep (k-perm pi, *log2e)
// blocks 254..637: embed (zh) | 638..1149: embedT (zhT)
// blocks 1150..1213: mask -> f32 bias table {0,-16384} + out[:,127]
__global__ __launch_bounds__(256) void prep_k(
    const float* __restrict__ values, const float* __restrict__ times,
    const int* __restrict__ mask,
    const float* __restrict__ omega, const float* __restrict__ alpha,
    const float* __restrict__ W1, const float* __restrict__ W2,
    unsigned short* __restrict__ zh, unsigned short* __restrict__ zhT,
    unsigned short* __restrict__ w1f, unsigned short* __restrict__ w2f,
    float* __restrict__ bias, float* __restrict__ out)
{
    const int bid = blockIdx.x;
    if (bid < 254) {
        // ---- weight fragment prep
        const int isW2 = (bid >= 127);
        const float* W = isW2 ? W2 : W1;
        unsigned short* Wf = isW2 ? w2f : w1f;
        const float scale = isW2 ? LOG2E : 1.0f;
        const int d = isW2 ? bid - 127 : bid;
        __shared__ float wl[DIN * DIN];
        const float* src = W + (size_t)d * DIN * DIN;
        for (int k = threadIdx.x; k < DIN * DIN / 4; k += 256)
            ((float4*)wl)[k] = ((const float4*)src)[k];
        __syncthreads();
        for (int rr = 0; rr < 2; ++rr) {
            int idx = threadIdx.x * 2 + rr;
            int fid = idx >> 6, l = idx & 63;
            int mt = fid >> 1, kt = fid & 1, g = l >> 4, c = l & 15;
            U8 t;
            #pragma unroll
            for (int e = 0; e < 8; ++e) {
                int row = isW2 ? (32 * kt + 16 * (e >> 2) + 4 * g + (e & 3))
                               : (32 * kt + 8 * g + e);
                t.h[e] = (_Float16)(wl[row * DIN + (16 * mt + c)] * scale);
            }
            *(uint4*)(Wf + ((size_t)(d * 8 + fid) * 64 + l) * 8) = t.u;
        }
    } else if (bid < 638) {
        // ---- embed: zh[n*s][64], chunk-swizzled
        int id = (bid - 254) * 256 + threadIdx.x;
        int ch = id & 7, ns = id >> 3;
        if (ns >= NSEQ * SLEN) return;
        int s = ns % SLEN;
        float t = times[ns];
        U8 o;
        #pragma unroll
        for (int e = 0; e < 8; ++e) {
            int i = ch * 8 + e;
            float r;
            if (i == 0)       r = omega[0] * t + alpha[0];
            else if (i == 63) r = values[ns];
            else              r = __sinf(t * omega[i] + alpha[i]);
            o.h[e] = (_Float16)r;
        }
        int csw = ch ^ (s & 7);
        *(uint4*)(zh + (size_t)ns * 64 + csw * 8) = o.u;
    } else if (bid < 1150) {
        // ---- embedT: zhT[n][j][s], row stride 56
        int id = (bid - 638) * 256 + threadIdx.x;
        int unit = id & 511, n = id >> 9;
        int sc = unit >> 6;
        if (sc >= 6) return;
        int j = unit & 63;
        int s0 = sc * 8;
        const float* tp = times + n * SLEN + s0;
        float4 t0 = *(const float4*)tp, t1 = *(const float4*)(tp + 4);
        float tv[8] = {t0.x, t0.y, t0.z, t0.w, t1.x, t1.y, t1.z, t1.w};
        U8 o;
        if (j == 0) {
            float om = omega[0], al = alpha[0];
            #pragma unroll
            for (int e = 0; e < 8; ++e) o.h[e] = (_Float16)(om * tv[e] + al);
        } else if (j == 63) {
            const float* vp = values + n * SLEN + s0;
            float4 v0 = *(const float4*)vp, v1 = *(const float4*)(vp + 4);
            float vv[8] = {v0.x, v0.y, v0.z, v0.w, v1.x, v1.y, v1.z, v1.w};
            #pragma unroll
            for (int e = 0; e < 8; ++e) o.h[e] = (_Float16)vv[e];
        } else {
            float om = omega[j], al = alpha[j];
            #pragma unroll
            for (int e = 0; e < 8; ++e) o.h[e] = (_Float16)__sinf(tv[e] * om + al);
        }
        *(uint4*)(zhT + (size_t)n * 3584 + j * 56 + s0) = o.u;
    } else {
        // ---- mask -> bias table {0,-16384} + out[:,127]
        int wid  = ((bid - 1150) * 256 + threadIdx.x) >> 6;   // n
        int lane = threadIdx.x & 63;
        if (wid >= NSEQ) return;
        int mv = (lane < SLEN) ? mask[wid * SLEN + lane] : 0;
        unsigned long long b = __ballot(mv != 0);
        if (lane < SLEN) bias[wid * SLEN + lane] = mv ? 0.f : -16384.f;
        if (lane == 0) out[wid * 128 + 127] = b ? 1.f : 0.f;
    }
}

// ---------------- K4: main fused kernel ----------------
// = r22 (512-thread blocks, launch_bounds(512,2) no-spill, zero LDS/barriers,
// XCD remap, rotated zf prefetch, b1-as-C, pack-relu, parallel ones-MFMA den,
// split fdot2 num, b2 deleted, DPP reduce, bias table, bare v_exp, no setprio)
// + NEW (single change): n-loop "#pragma unroll 2" — lets the scheduler
//   software-pipeline unit n's back-half (L2/softmax: uses pk only) with unit
//   n+1's front-half (L1 MFMAs: uses zf', writes aH'). r22 body = 96 VGPR,
//   ~32 regs headroom to the 128 cap funds the overlap. (r23's ztv-hoist was
//   neutral and is dropped to maximize headroom.)
__global__ __launch_bounds__(512, 2) void filter_k(
    const unsigned short* __restrict__ zh,
    const unsigned short* __restrict__ zhT,
    const float* __restrict__ bias,
    const unsigned short* __restrict__ w1f, const unsigned short* __restrict__ w2f,
    const float* __restrict__ b1,
    float* __restrict__ out)
{
    const int tid = threadIdx.x;
    const int w = tid >> 6, lane = tid & 63;
    const int g = lane >> 4, c = lane & 15;

    // XCD-aware remap: 512 blocks; xcd = lin%8, slot = lin/8 (0..63)
    const int lin   = blockIdx.y * 32 + blockIdx.x;
    const int xcd   = lin & 7, slot = lin >> 3;
    const int octet = xcd * 2 + (slot & 1);     // 0..15 (2 octets per XCD)
    const int nchk  = slot >> 1;                // 0..31
    const int d = octet * 8 + w;
    if (d >= 127) return;                       // whole-wave exit; no barriers
    const int nb = nchk * NCH;

    // per-d constants (reused across 8 n's)
    half8 w1fr[8], w2fr[8];
    #pragma unroll
    for (int f = 0; f < 8; ++f) {
        w1fr[f] = *(const half8*)(w1f + ((size_t)(d * 8 + f) * 64 + lane) * 8);
        w2fr[f] = *(const half8*)(w2f + ((size_t)(d * 8 + f) * 64 + lane) * 8);
    }
    f32x4 b1q[4];
    #pragma unroll
    for (int hm = 0; hm < 4; ++hm)
        b1q[hm] = *(const f32x4*)(b1 + d * DIN + 16 * hm + 4 * g);

    // hoisted global-address offsets (element units)
    int zoff[2][3];   // b128 frag reads: row s=16st+c, chunk (4kt+g)^(s&7)
    #pragma unroll
    for (int kt = 0; kt < 2; ++kt)
        #pragma unroll
        for (int st = 0; st < 3; ++st) {
            int s = 16 * st + c;
            zoff[kt][st] = s * 64 + (((4 * kt + g) ^ (s & 7)) << 3);
        }
    const int ztbase = c * 56 + 4 * g;   // zT: row j=16jt+c, s=16st+4g

    const fp16x2 zero2 = {(__fp16)0.f, (__fp16)0.f};
    U8 ones;
    #pragma unroll
    for (int e = 0; e < 8; ++e) ones.h[e] = (_Float16)1.f;
    const f32x4 zero4 = {0.f, 0.f, 0.f, 0.f};

    // ---- preload unit 0's zf (rotation seed)
    half8 zf[2][3];
    {
        const unsigned short* zl = zh + (size_t)nb * 3072;
        #pragma unroll
        for (int kt = 0; kt < 2; ++kt)
            #pragma unroll
            for (int st = 0; st < 3; ++st)
                zf[kt][st] = *(const half8*)(zl + zoff[kt][st]);
    }

    #pragma unroll 2
    for (int ni = 0; ni < NCH; ++ni) {
        const int n = nb + ni;
        const unsigned short* zt = zhT + (size_t)n * 3584;

        // mask bias per (st): s = 16st+4g+r, from precomputed f32 table
        const float* bn = bias + n * SLEN;
        f32x4 binit[3];
        #pragma unroll
        for (int st = 0; st < 3; ++st)
            binit[st] = *(const f32x4*)(bn + 16 * st + 4 * g);

        // ---- layer 1: H^T = W1^T x Z^T (b1 enters as kt=0's C-operand)
        f32x4 aH[4][3];
        #pragma unroll
        for (int hm = 0; hm < 4; ++hm)
            #pragma unroll
            for (int st = 0; st < 3; ++st) {
                aH[hm][st] = __builtin_amdgcn_mfma_f32_16x16x32_f16(
                    w1fr[hm * 2 + 0], zf[0][st], b1q[hm], 0, 0, 0);
                aH[hm][st] = __builtin_amdgcn_mfma_f32_16x16x32_f16(
                    w1fr[hm * 2 + 1], zf[1][st], aH[hm][st], 0, 0, 0);
            }

        // ---- rotation: zf consumed -> issue next unit's zf now
        if (ni + 1 < NCH) {
            const unsigned short* zl = zh + (size_t)(n + 1) * 3072;
            #pragma unroll
            for (int kt = 0; kt < 2; ++kt)
                #pragma unroll
                for (int st = 0; st < 3; ++st)
                    zf[kt][st] = *(const half8*)(zl + zoff[kt][st]);
        }

        // pack-then-relu: cvt_pkrtz -> packed max with 0 (registers only)
        unsigned int pk[4][3][2];
        #pragma unroll
        for (int hm = 0; hm < 4; ++hm)
            #pragma unroll
            for (int st = 0; st < 3; ++st) {
                UCV a, b;
                a.f = __builtin_elementwise_max(
                    __builtin_amdgcn_cvt_pkrtz(aH[hm][st][0], aH[hm][st][1]), zero2);
                b.f = __builtin_elementwise_max(
                    __builtin_amdgcn_cvt_pkrtz(aH[hm][st][2], aH[hm][st][3]), zero2);
                pk[hm][st][0] = a.i;
                pk[hm][st][1] = b.i;
            }

        // ---- per-jt: L2 MFMA (k-permuted, A lane-local; binit as C) +
        //      exp/pack + parallel ones-MFMA den + split fdot2 num
        float part = 0.f;
        #pragma unroll
        for (int jt = 0; jt < 4; ++jt) {
            f32x4 aL3[3];
            #pragma unroll
            for (int st = 0; st < 3; ++st) {
                U8 hfu;
                hfu.w[0] = pk[0][st][0];
                hfu.w[1] = pk[0][st][1];
                hfu.w[2] = pk[1][st][0];
                hfu.w[3] = pk[1][st][1];
                aL3[st] = __builtin_amdgcn_mfma_f32_16x16x32_f16(
                    hfu.v, w2fr[jt * 2 + 0], binit[st], 0, 0, 0);
                hfu.w[0] = pk[2][st][0];
                hfu.w[1] = pk[2][st][1];
                hfu.w[2] = pk[3][st][0];
                hfu.w[3] = pk[3][st][1];
                aL3[st] = __builtin_amdgcn_mfma_f32_16x16x32_f16(
                    hfu.v, w2fr[jt * 2 + 1], aL3[st], 0, 0, 0);
            }
            // exp -> packed f16 e-words (bare v_exp_f32)
            UCV p01[3], p23[3];
            #pragma unroll
            for (int st = 0; st < 3; ++st) {
                float v0 = __builtin_amdgcn_exp2f(aL3[st][0]);
                float v1 = __builtin_amdgcn_exp2f(aL3[st][1]);
                float v2 = __builtin_amdgcn_exp2f(aL3[st][2]);
                float v3 = __builtin_amdgcn_exp2f(aL3[st][3]);
                p01[st].f = __builtin_amdgcn_cvt_pkrtz(v0, v1);
                p23[st].f = __builtin_amdgcn_cvt_pkrtz(v2, v3);
            }
            // den via TWO PARALLEL ones-MFMAs + scalar add (depth 1)
            U8 ef0, ef1;
            ef0.w[0] = p01[0].i; ef0.w[1] = p23[0].i;
            ef0.w[2] = p01[1].i; ef0.w[3] = p23[1].i;
            ef1.w[0] = p01[2].i; ef1.w[1] = p23[2].i;
            ef1.w[2] = 0u;       ef1.w[3] = 0u;
            f32x4 dva = __builtin_amdgcn_mfma_f32_16x16x32_f16(
                ones.v, ef0.v, zero4, 0, 0, 0);
            f32x4 dvb = __builtin_amdgcn_mfma_f32_16x16x32_f16(
                ones.v, ef1.v, zero4, 0, 0, 0);
            float den = dva[0] + dvb[0];
            // num via two parallel 3-deep fdot2 chains
            float numa = 0.f, numb = 0.f;
            {
                U2 zu0, zu1, zu2;
                zu0.u = *(const uint2*)(zt + ztbase + jt * 896 + 0 * 16);
                zu1.u = *(const uint2*)(zt + ztbase + jt * 896 + 1 * 16);
                zu2.u = *(const uint2*)(zt + ztbase + jt * 896 + 2 * 16);
                UCV za, zb;
                za.i = zu0.u.x; zb.i = zu0.u.y;
                numa = __builtin_amdgcn_fdot2(p01[0].h, za.h, numa, false);
                numb = __builtin_amdgcn_fdot2(p23[0].h, zb.h, numb, false);
                za.i = zu1.u.x; zb.i = zu1.u.y;
                numa = __builtin_amdgcn_fdot2(p01[1].h, za.h, numa, false);
                numb = __builtin_amdgcn_fdot2(p23[1].h, zb.h, numb, false);
                za.i = zu2.u.x; zb.i = zu2.u.y;
                numa = __builtin_amdgcn_fdot2(p01[2].h, za.h, numa, false);
                numb = __builtin_amdgcn_fdot2(p23[2].h, zb.h, numb, false);
            }
            part = fmaf(numa + numb, __builtin_amdgcn_rcpf(den), part);
        }
        // ---- DPP 64-lane reduce (VALU only, no DS); total lands in lane 63
        part = wave_sum_dpp(part);
        if (lane == 63) out[n * 128 + d] = part;
    }
}

extern "C" void kernel_launch(void* const* d_in, const int* in_sizes, int n_in,
                              void* d_out, int out_size, void* d_ws, size_t ws_size,
                              hipStream_t stream) {
    const float* values = (const float*)d_in[0];
    const float* times  = (const float*)d_in[1];
    const int*   mask   = (const int*)d_in[2];
    const float* omega  = (const float*)d_in[3];
    const float* alpha  = (const float*)d_in[4];
    const float* W1     = (const float*)d_in[5];
    const float* b1     = (const float*)d_in[6];
    const float* W2     = (const float*)d_in[7];
    // b2 (d_in[8]) cancels in softmax (constant along s). Not read.
    float* out = (float*)d_out;

    unsigned short* zh  = (unsigned short*)d_ws;                 // 786432 f16
    unsigned short* zhT = zh  + (size_t)786432;                  // 917504 f16
    unsigned short* w1f = zhT + (size_t)917504;                  // 520192 f16
    unsigned short* w2f = w1f + (size_t)520192;                  // 520192 f16
    float* bias = (float*)(w2f + (size_t)520192);                // 12288 f32

    prep_k<<<dim3(1214), dim3(256), 0, stream>>>(
        values, times, mask, omega, alpha, W1, W2,
        zh, zhT, w1f, w2f, bias, out);
    filter_k<<<dim3(32, 16), dim3(512), 0, stream>>>(
        zh, zhT, bias, w1f, w2f, b1, out);
}